// Round 1
// baseline (189.023 us; speedup 1.0000x reference)
//
#include <hip/hip_runtime.h>

// ShuffleNet unit: conv1(1x1,G=3,480->120)+BN+ReLU -> dw3x3+BN -> shuffle ->
// conv3(1x1,G=3,120->480)+BN+ReLU -> +x.   All fp32, NCHW.
// B=64, H=W=28 -> 50176 pixels = 196 * 256 exactly.

namespace {
constexpr int CIN   = 480;
constexpr int MID   = 120;
constexpr int HH    = 28;
constexpr int WWc   = 28;
constexpr int HWP   = 784;
constexpr int ICPG1 = 160;   // 480/3
constexpr int ICPG3 = 40;    // 120/3
constexpr float EPSV = 1e-5f;
constexpr int OCB1  = 20;    // out-channels per thread, kernel 1 (120/20 = 6 blocksY)
constexpr int OCB3  = 20;    // out-channels per thread, kernel 3 (480/20 = 24 blocksY)
}

// ---------- K1: 1x1 grouped conv + BN + ReLU ----------
__global__ __launch_bounds__(256) void k1_conv1(
    const float* __restrict__ x,  const float* __restrict__ w1,
    const float* __restrict__ g1, const float* __restrict__ b1,
    const float* __restrict__ m1, const float* __restrict__ v1,
    float* __restrict__ tmp1)
{
    const int p   = blockIdx.x * 256 + threadIdx.x;   // 0..50175 (b*784+hw)
    const int b   = p / HWP;
    const int hw  = p - b * HWP;
    const int oc0 = blockIdx.y * OCB1;                // 20 | 40 -> group-uniform
    const int g   = oc0 / 40;
    const float* __restrict__ xin = x + ((size_t)b * CIN + (size_t)g * ICPG1) * HWP + hw;

    float acc[OCB1];
#pragma unroll
    for (int j = 0; j < OCB1; ++j) acc[j] = 0.f;

    for (int ic = 0; ic < ICPG1; ic += 4) {
        const float xv0 = xin[(size_t)(ic + 0) * HWP];
        const float xv1 = xin[(size_t)(ic + 1) * HWP];
        const float xv2 = xin[(size_t)(ic + 2) * HWP];
        const float xv3 = xin[(size_t)(ic + 3) * HWP];
#pragma unroll
        for (int j = 0; j < OCB1; ++j) {
            const float4 wv = *reinterpret_cast<const float4*>(w1 + (oc0 + j) * ICPG1 + ic);
            float a = acc[j];
            a = fmaf(xv0, wv.x, a);
            a = fmaf(xv1, wv.y, a);
            a = fmaf(xv2, wv.z, a);
            a = fmaf(xv3, wv.w, a);
            acc[j] = a;
        }
    }
#pragma unroll
    for (int j = 0; j < OCB1; ++j) {
        const int oc = oc0 + j;
        const float s  = g1[oc] * rsqrtf(v1[oc] + EPSV);
        const float sh = fmaf(-m1[oc], s, b1[oc]);
        float val = fmaf(acc[j], s, sh);
        val = val > 0.f ? val : 0.f;
        tmp1[((size_t)b * MID + oc) * HWP + hw] = val;
    }
}

// ---------- K2: depthwise 3x3 + BN, shuffle folded into output channel ----------
__global__ __launch_bounds__(256) void k2_dw(
    const float* __restrict__ tmp1, const float* __restrict__ w2,
    const float* __restrict__ g2,   const float* __restrict__ b2,
    const float* __restrict__ m2,   const float* __restrict__ v2,
    float* __restrict__ tmp2)
{
    const int p  = blockIdx.x * 256 + threadIdx.x;
    const int b  = p / HWP;
    const int hw = p - b * HWP;
    const int h  = hw / WWc;
    const int w  = hw - h * WWc;
    const int c  = blockIdx.y;                        // 0..119 (pre-shuffle channel)
    const float* __restrict__ in = tmp1 + ((size_t)b * MID + c) * HWP;

    float acc = 0.f;
#pragma unroll
    for (int dh = -1; dh <= 1; ++dh) {
        const int hh = h + dh;
        if (hh < 0 || hh >= HH) continue;
#pragma unroll
        for (int dw = -1; dw <= 1; ++dw) {
            const int ww = w + dw;
            if (ww < 0 || ww >= WWc) continue;
            acc = fmaf(in[hh * WWc + ww], w2[c * 9 + (dh + 1) * 3 + (dw + 1)], acc);
        }
    }
    const float s  = g2[c] * rsqrtf(v2[c] + EPSV);
    const float val = fmaf(acc, s, fmaf(-m2[c], s, b2[c]));
    // channel shuffle: orig c = g*40 + c2  ->  shuffled pos c2*3 + g
    const int cs = (c % 40) * 3 + (c / 40);
    tmp2[((size_t)b * MID + cs) * HWP + hw] = val;
}

// ---------- K3: 1x1 grouped conv + BN + ReLU + shortcut ----------
__global__ __launch_bounds__(256) void k3_conv3(
    const float* __restrict__ tmp2, const float* __restrict__ w3,
    const float* __restrict__ g3,   const float* __restrict__ b3,
    const float* __restrict__ m3,   const float* __restrict__ v3,
    const float* __restrict__ x,    float* __restrict__ out)
{
    const int p   = blockIdx.x * 256 + threadIdx.x;
    const int b   = p / HWP;
    const int hw  = p - b * HWP;
    const int oc0 = blockIdx.y * OCB3;                // 20 | 160 -> group-uniform
    const int g   = oc0 / 160;
    const float* __restrict__ in = tmp2 + ((size_t)b * MID + (size_t)g * ICPG3) * HWP + hw;

    float acc[OCB3];
#pragma unroll
    for (int j = 0; j < OCB3; ++j) acc[j] = 0.f;

    for (int ic = 0; ic < ICPG3; ic += 4) {
        const float xv0 = in[(size_t)(ic + 0) * HWP];
        const float xv1 = in[(size_t)(ic + 1) * HWP];
        const float xv2 = in[(size_t)(ic + 2) * HWP];
        const float xv3 = in[(size_t)(ic + 3) * HWP];
#pragma unroll
        for (int j = 0; j < OCB3; ++j) {
            const float4 wv = *reinterpret_cast<const float4*>(w3 + (oc0 + j) * ICPG3 + ic);
            float a = acc[j];
            a = fmaf(xv0, wv.x, a);
            a = fmaf(xv1, wv.y, a);
            a = fmaf(xv2, wv.z, a);
            a = fmaf(xv3, wv.w, a);
            acc[j] = a;
        }
    }
#pragma unroll
    for (int j = 0; j < OCB3; ++j) {
        const int oc = oc0 + j;
        const float s  = g3[oc] * rsqrtf(v3[oc] + EPSV);
        const float sh = fmaf(-m3[oc], s, b3[oc]);
        float val = fmaf(acc[j], s, sh);
        val = val > 0.f ? val : 0.f;
        const size_t oidx = ((size_t)b * CIN + oc) * HWP + hw;
        out[oidx] = val + x[oidx];
    }
}

extern "C" void kernel_launch(void* const* d_in, const int* in_sizes, int n_in,
                              void* d_out, int out_size, void* d_ws, size_t ws_size,
                              hipStream_t stream) {
    const float* x  = (const float*)d_in[0];
    const float* w1 = (const float*)d_in[1];
    const float* g1 = (const float*)d_in[2];
    const float* b1 = (const float*)d_in[3];
    const float* m1 = (const float*)d_in[4];
    const float* v1 = (const float*)d_in[5];
    const float* w2 = (const float*)d_in[6];
    const float* g2 = (const float*)d_in[7];
    const float* b2 = (const float*)d_in[8];
    const float* m2 = (const float*)d_in[9];
    const float* v2 = (const float*)d_in[10];
    const float* w3 = (const float*)d_in[11];
    const float* g3 = (const float*)d_in[12];
    const float* b3 = (const float*)d_in[13];
    const float* m3 = (const float*)d_in[14];
    const float* v3 = (const float*)d_in[15];
    float* out = (float*)d_out;

    float* tmp1 = (float*)d_ws;                         // 64*120*784 floats = 24.1 MB
    float* tmp2 = tmp1 + (size_t)64 * MID * HWP;        // another 24.1 MB

    dim3 blk(256, 1, 1);
    k1_conv1<<<dim3(196, MID / OCB1, 1), blk, 0, stream>>>(x, w1, g1, b1, m1, v1, tmp1);
    k2_dw  <<<dim3(196, MID, 1),          blk, 0, stream>>>(tmp1, w2, g2, b2, m2, v2, tmp2);
    k3_conv3<<<dim3(196, CIN / OCB3, 1),  blk, 0, stream>>>(tmp2, w3, g3, b3, m3, v3, x, out);
}